// Round 4
// baseline (367.541 us; speedup 1.0000x reference)
//
#include <hip/hip_runtime.h>
#include <math.h>

// Problem constants (KimiLinearKDADecode): HK=HV=32, D=128, K=4, B=128
#define NHK   32
#define NHV   32
#define DDIM  128
#define NB    128
#define QKVC  12288   // (2*HK+HV)*D
#define NTILE (NB * NHV)   // 4096 (b,h) tiles

typedef float f32x4 __attribute__((ext_vector_type(4)));

__device__ __forceinline__ float sigmoid_f(float x) { return 1.0f / (1.0f + expf(-x)); }
__device__ __forceinline__ float silu_f(float x)    { return x * sigmoid_f(x); }
__device__ __forceinline__ float softplus_f(float x){ return (x > 20.0f) ? x : log1pf(expf(x)); }

// ---------------------------------------------------------------------------
// Kernel 1: per-(b,h) prologue. Computes the fused column weight
//   w[k]   = wq[k] - c*wk[k],   c = (qn.kn)*dscale*sigmoid(beta)
//   bias[v]= c * v_silu[v]
// and stores both into d_ws:  ws[bh*256 + k] = w,  ws[bh*256 + 128 + v] = bias.
// All 4096 blocks' dependent-latency chains overlap; BW cost ~27 MB.
// ---------------------------------------------------------------------------
__global__ __launch_bounds__(128)
void kda_prep(const float* __restrict__ mixed,    // (B, 12288)
              const float* __restrict__ fgate,    // (B, 4096)
              const float* __restrict__ beta,     // (B, 32)
              const float* __restrict__ cstate,   // (B, 12288, 3)
              const float* __restrict__ cweight,  // (12288, 4)
              const float* __restrict__ A_log,    // (32,)
              const float* __restrict__ dt_bias,  // (4096,)
              float* __restrict__ wb)             // (4096, 256) workspace
{
    const int bh  = blockIdx.x;
    const int b   = bh >> 5;
    const int h   = bh & 31;
    const int tid = threadIdx.x;   // 0..127

    __shared__ float part[2][3];

    const int cq = h * DDIM + tid;
    const int ck = (NHK + h) * DDIM + tid;
    const int cv = (2 * NHK + h) * DDIM + tid;
    const size_t b3 = (size_t)b * QKVC * 3;
    const size_t b1 = (size_t)b * QKVC;

    // conv-state + weights + current token
    float cs_q[3], cs_k[3], cs_v[3];
    #pragma unroll
    for (int j = 0; j < 3; ++j) {
        cs_q[j] = cstate[b3 + (size_t)cq * 3 + j];
        cs_k[j] = cstate[b3 + (size_t)ck * 3 + j];
        cs_v[j] = cstate[b3 + (size_t)cv * 3 + j];
    }
    const float4 cw_q = *reinterpret_cast<const float4*>(cweight + (size_t)cq * 4);
    const float4 cw_k = *reinterpret_cast<const float4*>(cweight + (size_t)ck * 4);
    const float4 cw_v = *reinterpret_cast<const float4*>(cweight + (size_t)cv * 4);
    const float mx_q = mixed[b1 + cq];
    const float mx_k = mixed[b1 + ck];
    const float mx_v = mixed[b1 + cv];
    const float fg   = fgate[(size_t)b * (NHV * DDIM) + h * DDIM + tid];
    const float dtb  = dt_bias[h * DDIM + tid];
    const float betav = beta[b * NHV + h];
    const float alog  = A_log[h];

    const float xq = silu_f(cs_q[0]*cw_q.x + cs_q[1]*cw_q.y + cs_q[2]*cw_q.z + mx_q*cw_q.w);
    const float xk = silu_f(cs_k[0]*cw_k.x + cs_k[1]*cw_k.y + cs_k[2]*cw_k.z + mx_k*cw_k.w);
    const float xv = silu_f(cs_v[0]*cw_v.x + cs_v[1]*cw_v.y + cs_v[2]*cw_v.z + mx_v*cw_v.w);

    // block reduction over 128 threads = 2 waves
    float a0 = xq * xq, a1 = xk * xk, a2 = xq * xk;
    #pragma unroll
    for (int off = 32; off; off >>= 1) {
        a0 += __shfl_xor(a0, off);
        a1 += __shfl_xor(a1, off);
        a2 += __shfl_xor(a2, off);
    }
    const int wid = tid >> 6;
    if ((tid & 63) == 0) { part[wid][0] = a0; part[wid][1] = a1; part[wid][2] = a2; }
    __syncthreads();
    const float q2  = part[0][0] + part[1][0];
    const float k2  = part[0][1] + part[1][1];
    const float qkd = part[0][2] + part[1][2];

    const float dscale = 0.08838834764831845f;   // 1/sqrt(128)
    const float rq = rsqrtf(q2 + 1e-6f);
    const float rk = rsqrtf(k2 + 1e-6f);
    const float c  = qkd * rq * rk * dscale * sigmoid_f(betav);  // (qn.kn)*sig(beta)

    const float g  = -expf(alog) * softplus_f(fg + dtb);
    const float eg = expf(g);
    const float wq = xq * rq * dscale * eg;
    const float wk = xk * rk * eg;

    float* W = wb + (size_t)bh * 256;
    W[tid]        = wq - c * wk;   // fused column weight
    W[DDIM + tid] = c * xv;        // output bias term
}

// ---------------------------------------------------------------------------
// Kernel 2: pure stream. One WAVE per (b,h) tile — no LDS, no barriers.
// Wave sweeps its 64 KB tile as 64 contiguous 1 KB chunks (copy-bench shape):
// chunk i = rows {2i, 2i+1}; lane reads float4 at chunk*1024B + lane*16B.
// Weight w[2i+half] via uniform-broadcast float2 load. Cross-half combine
// with 4 shfl_xor(32); lanes<32 add bias and store coalesced float4.
// ---------------------------------------------------------------------------
__global__ __launch_bounds__(256)
void kda_stream(const float* __restrict__ ssm,   // (4096, 128, 128)
                const float* __restrict__ wb,    // (4096, 256)
                float* __restrict__ out)         // (4096, 128)
{
    const int wid  = threadIdx.x >> 6;
    const int lane = threadIdx.x & 63;
    const int tile = (blockIdx.x << 2) | wid;    // 0..4095

    const float* W  = wb  + (size_t)tile * 256;
    const float* Sb = ssm + (size_t)tile * (DDIM * DDIM);
    const float* base = Sb + lane * 4;

    const int half = lane >> 5;
    const int c4   = (lane & 31) * 4;

    f32x4 acc0 = {0.f,0.f,0.f,0.f}, acc1 = {0.f,0.f,0.f,0.f};
    f32x4 acc2 = {0.f,0.f,0.f,0.f}, acc3 = {0.f,0.f,0.f,0.f};

    #pragma unroll 2
    for (int i = 0; i < 64; i += 4) {
        const f32x4 s0 = __builtin_nontemporal_load(reinterpret_cast<const f32x4*>(base + (size_t)(i+0) * 256));
        const f32x4 s1 = __builtin_nontemporal_load(reinterpret_cast<const f32x4*>(base + (size_t)(i+1) * 256));
        const f32x4 s2 = __builtin_nontemporal_load(reinterpret_cast<const f32x4*>(base + (size_t)(i+2) * 256));
        const f32x4 s3 = __builtin_nontemporal_load(reinterpret_cast<const f32x4*>(base + (size_t)(i+3) * 256));
        const float2 wp0 = *reinterpret_cast<const float2*>(W + 2*(i+0));
        const float2 wp1 = *reinterpret_cast<const float2*>(W + 2*(i+1));
        const float2 wp2 = *reinterpret_cast<const float2*>(W + 2*(i+2));
        const float2 wp3 = *reinterpret_cast<const float2*>(W + 2*(i+3));
        const float w0 = half ? wp0.y : wp0.x;
        const float w1 = half ? wp1.y : wp1.x;
        const float w2 = half ? wp2.y : wp2.x;
        const float w3 = half ? wp3.y : wp3.x;
        acc0.x = fmaf(w0, s0.x, acc0.x); acc0.y = fmaf(w0, s0.y, acc0.y);
        acc0.z = fmaf(w0, s0.z, acc0.z); acc0.w = fmaf(w0, s0.w, acc0.w);
        acc1.x = fmaf(w1, s1.x, acc1.x); acc1.y = fmaf(w1, s1.y, acc1.y);
        acc1.z = fmaf(w1, s1.z, acc1.z); acc1.w = fmaf(w1, s1.w, acc1.w);
        acc2.x = fmaf(w2, s2.x, acc2.x); acc2.y = fmaf(w2, s2.y, acc2.y);
        acc2.z = fmaf(w2, s2.z, acc2.z); acc2.w = fmaf(w2, s2.w, acc2.w);
        acc3.x = fmaf(w3, s3.x, acc3.x); acc3.y = fmaf(w3, s3.y, acc3.y);
        acc3.z = fmaf(w3, s3.z, acc3.z); acc3.w = fmaf(w3, s3.w, acc3.w);
    }

    f32x4 acc;
    acc.x = (acc0.x + acc1.x) + (acc2.x + acc3.x);
    acc.y = (acc0.y + acc1.y) + (acc2.y + acc3.y);
    acc.z = (acc0.z + acc1.z) + (acc2.z + acc3.z);
    acc.w = (acc0.w + acc1.w) + (acc2.w + acc3.w);

    // lanes l and l^32 hold even/odd-row partials of the same 4 columns
    acc.x += __shfl_xor(acc.x, 32);
    acc.y += __shfl_xor(acc.y, 32);
    acc.z += __shfl_xor(acc.z, 32);
    acc.w += __shfl_xor(acc.w, 32);

    if (half == 0) {
        const f32x4 bias = *reinterpret_cast<const f32x4*>(W + DDIM + c4);
        f32x4 o;
        o.x = acc.x + bias.x; o.y = acc.y + bias.y;
        o.z = acc.z + bias.z; o.w = acc.w + bias.w;
        *reinterpret_cast<f32x4*>(out + (size_t)tile * DDIM + c4) = o;
    }
}

extern "C" void kernel_launch(void* const* d_in, const int* in_sizes, int n_in,
                              void* d_out, int out_size, void* d_ws, size_t ws_size,
                              hipStream_t stream) {
    const float* mixed   = (const float*)d_in[0];
    const float* fgate   = (const float*)d_in[1];
    const float* beta    = (const float*)d_in[2];
    const float* cstate  = (const float*)d_in[3];
    const float* cweight = (const float*)d_in[4];
    const float* ssm     = (const float*)d_in[5];
    const float* A_log   = (const float*)d_in[6];
    const float* dt_bias = (const float*)d_in[7];
    float* out = (float*)d_out;
    float* wb  = (float*)d_ws;   // 4096 * 256 floats = 4 MB

    kda_prep<<<NTILE, 128, 0, stream>>>(mixed, fgate, beta, cstate, cweight,
                                        A_log, dt_bias, wb);
    kda_stream<<<NTILE / 4, 256, 0, stream>>>(ssm, wb, out);
}